// Round 9
// baseline (63.172 us; speedup 1.0000x reference)
//
#include <hip/hip_runtime.h>

typedef _Float16 f16;
typedef f16   f16x4 __attribute__((ext_vector_type(4)));
typedef f16   f16x8 __attribute__((ext_vector_type(8)));
typedef float f32x4 __attribute__((ext_vector_type(4)));

#define E 512
#define BM 128           /* rows per block (halves per-block weight re-reads) */
#define NT 16            /* K-steps of 32 */

// ---------------------------------------------------------------------------
// Weight convert+pack: W (fp32 [512][512] row-major, y = x@W^T) ->
// f16 packed [t=k/32][n=512][k%32]: a wave's fragment load is 1KB contiguous.
// ---------------------------------------------------------------------------
__global__ void convert_w_kernel(const float* __restrict__ wq,
                                 const float* __restrict__ wo,
                                 f16* __restrict__ q_p,
                                 f16* __restrict__ o_p) {
    int i = blockIdx.x * blockDim.x + threadIdx.x;   // 65536 threads
    const int half = (512 * 512) / 8;                // 32768 groups of 8
    const float* src; f16* dst;
    if (i < half) { src = wq; dst = q_p; }
    else          { src = wo; dst = o_p; i -= half; }
    const int n = i >> 6, kg = i & 63;               // 8-elem k-group
    const float* s = src + (size_t)n * 512 + kg * 8;
    float4 a = *(const float4*)s, b = *(const float4*)(s + 4);
    f16x8 h;
#pragma unroll
    for (int q = 0; q < 4; ++q) { h[q] = (f16)a[q]; h[4 + q] = (f16)b[q]; }
    const int t = kg >> 2, w = kg & 3;
    *(f16x8*)&dst[(size_t)t * 16384 + n * 32 + w * 8] = h;
}

// ---------------------------------------------------------------------------
// Fused: out = cumprod8(cos(x @ Wq^T)) @ Wo^T.  One block = 128 rows, 16 waves
// (wave grid 2 m-halves x 8 n-groups; wave tile 64m x 64n, same regs as r8).
// Halved weight L2 traffic: 256 blocks x 1 MB (was 512); the m-pair waves
// reading the same n-slice hit L1 (per-step pair working set 4 KB).
// LDS 128 KB aliased x/meas tile = 64 KB static (rows 0-63) + 64 KB dynamic
// (rows 64-127); each wave touches exactly one half (mi-uniform base select).
//   stage x -> T; barrier; phase1 (no K-loop barriers, weight ping-pong
//   prefetch depth 2); cumprod -> 32 VGPR; barrier; meas -> T; barrier;
//   phase2; f32x4 stores.
// Swapped-operand MFMA: m = lane&15, n = (lane>>4)*4 + reg.
// 1 block/CU = 16 waves = 4/SIMD (same occupancy as r8 -> isolates traffic).
// ---------------------------------------------------------------------------
__global__ __launch_bounds__(1024, 4)
void fused_kernel(const float* __restrict__ X,
                  const f16* __restrict__ Wq,   // packed [16][512][32]
                  const f16* __restrict__ Wo,   // packed [16][512][32]
                  float* __restrict__ Out) {
    __shared__ __align__(16) char Tlo[64 * 1024];   // rows 0-63
    extern __shared__ __align__(16) char Thi[];     // rows 64-127 (64 KB dyn)

    const int tid  = threadIdx.x;
    const int lane = tid & 63;
    const int wave = tid >> 6;        // 0..15
    const int fr   = lane & 15;
    const int kq   = lane >> 4;
    const int mi   = wave & 1;        // m-half: rows [mi*64, +64)
    const int nj   = wave >> 1;       // n-group: cols [nj*64, +64)

    // XCD-chunked bijective swizzle (gridDim.x % 8 == 0)
    const int bid = blockIdx.x;
    const int chunk = gridDim.x >> 3;
    const int swz = (bid & 7) * chunk + (bid >> 3);
    const int m0 = swz * BM;

    // ---- stage x: wave w -> rows w*8..w*8+7 (pre-swizzled col, linear write) ----
    {
        char* sbase = (wave < 8) ? Tlo : Thi;
        const int rbase = (wave < 8) ? wave * 8 : (wave - 8) * 8;  // local row
        const int gbase = wave * 8;                                 // global row
        float4 xa[8], xb[8];
#pragma unroll
        for (int c = 0; c < 8; ++c) {
            const int grow = gbase + c;
            const int col = (lane ^ (grow & 7)) * 8;
            const float* s = X + (size_t)(m0 + grow) * E + col;
            xa[c] = *(const float4*)s;
            xb[c] = *(const float4*)(s + 4);
        }
#pragma unroll
        for (int c = 0; c < 8; ++c) {
            f16x8 h;
#pragma unroll
            for (int q = 0; q < 4; ++q) { h[q] = (f16)xa[c][q]; h[4 + q] = (f16)xb[c][q]; }
            *(f16x8*)(sbase + (rbase + c) * 1024 + lane * 16) = h;
        }
    }
    __syncthreads();

    char* tbase = mi ? Thi : Tlo;   // this wave's half (all its A-rows live here)

    // ---- phase 1: q = x @ Wq^T -> meas regs ----
    f16x4 mr[4][4];                    // transient meas, 32 VGPR
    {
        const int nb = nj * 64;
        f32x4 acc[4][4] = {};
        f16x8 bw[2][4];
        const f16* wbase = Wq + (size_t)(nb + fr) * 32 + kq * 8;
#pragma unroll
        for (int j = 0; j < 4; ++j) bw[0][j] = *(const f16x8*)(wbase + j * 512);
#pragma unroll
        for (int j = 0; j < 4; ++j) bw[1][j] = *(const f16x8*)(wbase + 16384 + j * 512);

#pragma unroll
        for (int t = 0; t < NT; ++t) {
            f16x8 afr[4];
#pragma unroll
            for (int i = 0; i < 4; ++i) {
                const int row = i * 16 + fr;            // local row in half
                const int c8  = t * 4 + kq;
                afr[i] = *(const f16x8*)(tbase + row * 1024 + ((c8 ^ (row & 7)) * 16));
            }
#pragma unroll
            for (int i = 0; i < 4; ++i)
#pragma unroll
                for (int j = 0; j < 4; ++j)
                    acc[i][j] = __builtin_amdgcn_mfma_f32_16x16x32_f16(
                        bw[t & 1][j], afr[i], acc[i][j], 0, 0, 0);
            if (t + 2 < NT) {   // refill consumed buffer (prefetch depth 2)
#pragma unroll
                for (int j = 0; j < 4; ++j)
                    bw[t & 1][j] = *(const f16x8*)(wbase + (size_t)(t + 2) * 16384 + j * 512);
            }
        }

        // cumprod(cos) over 8-wide n-groups; partner lane^16 holds other half
#pragma unroll
        for (int i = 0; i < 4; ++i)
#pragma unroll
            for (int j = 0; j < 4; ++j) {
                float c0 = __cosf(acc[i][j][0]);
                float c1 = c0 * __cosf(acc[i][j][1]);
                float c2 = c1 * __cosf(acc[i][j][2]);
                float c3 = c2 * __cosf(acc[i][j][3]);
                float ptot = __shfl_xor(c3, 16, 64);
                float f = (kq & 1) ? ptot : 1.0f;    // odd quad = upper half
                mr[i][j] = f16x4{ (f16)(c0 * f), (f16)(c1 * f),
                                  (f16)(c2 * f), (f16)(c3 * f) };
            }
    }
    __syncthreads();   // all waves done READING x

    // ---- meas regs -> T (same swizzled layout; rows stay in wave's half) ----
    {
        const int nb8 = (nj * 64) >> 3;
#pragma unroll
        for (int i = 0; i < 4; ++i) {
            const int row = i * 16 + fr;
#pragma unroll
            for (int j = 0; j < 4; ++j) {
                const int c8 = nb8 + j * 2 + (kq >> 1);
                *(f16x4*)(tbase + row * 1024 + ((c8 ^ (row & 7)) * 16) + (kq & 1) * 8)
                    = mr[i][j];
            }
        }
    }
    __syncthreads();

    // ---- phase 2: out = meas @ Wo^T ----
    {
        const int fb = nj * 64;
        f32x4 acc[4][4] = {};
        f16x8 bw[2][4];
        const f16* wbase = Wo + (size_t)(fb + fr) * 32 + kq * 8;
#pragma unroll
        for (int j = 0; j < 4; ++j) bw[0][j] = *(const f16x8*)(wbase + j * 512);
#pragma unroll
        for (int j = 0; j < 4; ++j) bw[1][j] = *(const f16x8*)(wbase + 16384 + j * 512);

#pragma unroll
        for (int t = 0; t < NT; ++t) {
            f16x8 afr[4];
#pragma unroll
            for (int i = 0; i < 4; ++i) {
                const int row = i * 16 + fr;
                const int c8  = t * 4 + kq;
                afr[i] = *(const f16x8*)(tbase + row * 1024 + ((c8 ^ (row & 7)) * 16));
            }
#pragma unroll
            for (int i = 0; i < 4; ++i)
#pragma unroll
                for (int j = 0; j < 4; ++j)
                    acc[i][j] = __builtin_amdgcn_mfma_f32_16x16x32_f16(
                        bw[t & 1][j], afr[i], acc[i][j], 0, 0, 0);
            if (t + 2 < NT) {
#pragma unroll
                for (int j = 0; j < 4; ++j)
                    bw[t & 1][j] = *(const f16x8*)(wbase + (size_t)(t + 2) * 16384 + j * 512);
            }
        }

        // store: 4 kq-lanes per row write 64B contiguous per (i,j)
#pragma unroll
        for (int i = 0; i < 4; ++i) {
            const int row = m0 + mi * 64 + i * 16 + fr;
#pragma unroll
            for (int j = 0; j < 4; ++j)
                *(f32x4*)&Out[(size_t)row * E + fb + j * 16 + kq * 4] = acc[i][j];
        }
    }
}

// ---------------------------------------------------------------------------
extern "C" void kernel_launch(void* const* d_in, const int* in_sizes, int n_in,
                              void* d_out, int out_size, void* d_ws, size_t ws_size,
                              hipStream_t stream) {
    const float* x  = (const float*)d_in[0];
    const float* Wq = (const float*)d_in[1];
    // d_in[2]=Wk, d_in[3]=Wv: dead compute in the reference
    const float* Wo = (const float*)d_in[4];

    const int M = in_sizes[0] / E;   // 32768

    f16* wq_p = (f16*)d_ws;          // 512 KB packed
    f16* wo_p = wq_p + 512 * 512;    // 512 KB packed

    convert_w_kernel<<<256, 256, 0, stream>>>(Wq, Wo, wq_p, wo_p);
    fused_kernel<<<M / BM, 1024, 64 * 1024, stream>>>(x, wq_p, wo_p, (float*)d_out);
}